// Round 8
// baseline (164.639 us; speedup 1.0000x reference)
//
#include <hip/hip_runtime.h>

#define NBATCH 8192
#define DD 512
#define NIDS 1000000
#define BCNT 4096
#define NCT 5
#define INV_TEMP 14.285714285714286f
#define EPSF 1.1920929e-07f

typedef __attribute__((ext_vector_type(8))) short bf16x8;
typedef __attribute__((ext_vector_type(4))) float f32x4;
typedef __attribute__((ext_vector_type(8))) unsigned short u16x8;

// ---------------- workspace layout (bytes) ----------------
#define OFF_POS    ((size_t)(32*1024))
#define OFF_RNK    ((size_t)(64*1024))
#define OFF_CNT    ((size_t)(96*1024))
#define OFF_ACC    ((size_t)(97*1024))
#define OFF_DA     ((size_t)(100*1024))
#define OFF_RA0    ((size_t)(132*1024))
#define OFF_RB0    ((size_t)(164*1024))
#define OFF_RA1    ((size_t)(196*1024))
#define OFF_RB1    ((size_t)(228*1024))
#define OFF_SIV    ((size_t)(260*1024))
#define OFF_STV    ((size_t)(292*1024))
#define OFF_WINI   ((size_t)(324*1024))
#define OFF_WINT   (OFF_WINI + 4000000)
#define OFF_MA     (OFF_WINT + 4000000)
#define MATB       ((size_t)(8192*512*2))
#define OFF_MB     (OFF_MA + MATB)
#define OFF_MC     (OFF_MB + MATB)
#define OFF_MD     (OFF_MC + MATB)

// Blocked-swizzled operand layout (proven 0-conflict in rounds 4/5):
// panel = row/128 (stride 65536 ushorts), K-tile kc = k/32 (stride 4096 ushorts),
// within-tile row-major [128][32] ushorts (64B rows); byte within row:
// (granule*16) ^ ((row&6)<<3)  — applied identically by writer and reader.

__device__ __forceinline__ unsigned short f2bf(float x) {
    unsigned int u = __float_as_uint(x);
    unsigned int r = (u + 0x7fffu + ((u >> 16) & 1u)) >> 16;
    return (unsigned short)r;
}

// K0: copy s_I/s_T into output, init winner arrays and accumulators
__global__ void k_init(const float* __restrict__ sI, const float* __restrict__ sT,
                       float* __restrict__ out, int* __restrict__ winI, int* __restrict__ winT,
                       float* __restrict__ rA0, float* __restrict__ rB0,
                       float* __restrict__ rA1, float* __restrict__ rB1,
                       float* __restrict__ acc) {
    int i = blockIdx.x * blockDim.x + threadIdx.x;
    if (i < NIDS) {
        out[1 + i] = sI[i];
        out[1 + NIDS + i] = sT[i];
        winI[i] = -1;
        winT[i] = -1;
    }
    if (i < NBATCH) { rA0[i] = 0.f; rB0[i] = 0.f; rA1[i] = 0.f; rB1[i] = 0.f; }
    if (i < 32) acc[i] = 0.f;
}

// K1: single-block stable compaction: pos list, rank array, counts
__global__ void k_compact(const int* __restrict__ slabel, int* __restrict__ pos,
                          int* __restrict__ rnk, int* __restrict__ cnts) {
    __shared__ int sums[1024];
    int tid = threadIdx.x;
    int flags[8];
    int c = 0;
    int base = tid * 8;
#pragma unroll
    for (int j = 0; j < 8; ++j) { flags[j] = (slabel[base + j] == 1); c += flags[j]; }
    sums[tid] = c;
    __syncthreads();
    for (int off = 1; off < 1024; off <<= 1) {
        int add = (tid >= off) ? sums[tid - off] : 0;
        __syncthreads();
        sums[tid] += add;
        __syncthreads();
    }
    int p = sums[tid] - c;  // exclusive prefix of pos count
#pragma unroll
    for (int j = 0; j < 8; ++j) {
        int idx = base + j;
        if (flags[j]) { pos[p] = idx; rnk[idx] = p; p++; }
        else rnk[idx] = idx - p;
    }
    if (tid == 0) { cnts[0] = sums[1023]; cnts[1] = NBATCH - sums[1023]; }
}

// K2: fused gather: read img[i],txt[i] once, diag dot, bf16-convert, route to
// (mA,mC) for pos rows / (mD,mB) for neg rows in blocked-swizzled layout.
__global__ __launch_bounds__(256) void k_gather(
        const float* __restrict__ img, const float* __restrict__ txt,
        const int* __restrict__ slabel, const int* __restrict__ rnk,
        unsigned short* __restrict__ mA, unsigned short* __restrict__ mB,
        unsigned short* __restrict__ mC, unsigned short* __restrict__ mD,
        float* __restrict__ dA) {
    int tid = threadIdx.x;
    int i = blockIdx.x * 4 + (tid >> 6);     // one wave per batch row
    int g = tid & 63;                         // 16B granule
    const float4* ip = (const float4*)(img + (size_t)i * DD) + g * 2;
    const float4* tp = (const float4*)(txt + (size_t)i * DD) + g * 2;
    float4 v0 = ip[0], v1 = ip[1], t0 = tp[0], t1 = tp[1];
    float part = v0.x * t0.x + v0.y * t0.y + v0.z * t0.z + v0.w * t0.w
               + v1.x * t1.x + v1.y * t1.y + v1.z * t1.z + v1.w * t1.w;
    for (int off = 32; off; off >>= 1) part += __shfl_xor(part, off);

    int lab = (slabel[i] == 1);
    int r = rnk[i];
    u16x8 oi, ot;
    oi[0] = f2bf(v0.x); oi[1] = f2bf(v0.y); oi[2] = f2bf(v0.z); oi[3] = f2bf(v0.w);
    oi[4] = f2bf(v1.x); oi[5] = f2bf(v1.y); oi[6] = f2bf(v1.z); oi[7] = f2bf(v1.w);
    ot[0] = f2bf(t0.x); ot[1] = f2bf(t0.y); ot[2] = f2bf(t0.z); ot[3] = f2bf(t0.w);
    ot[4] = f2bf(t1.x); ot[5] = f2bf(t1.y); ot[6] = f2bf(t1.z); ot[7] = f2bf(t1.w);

    int kc = g >> 2, gg = g & 3, rl = r & 127;
    int kb = (gg * 16) ^ ((rl & 6) << 3);    // swizzled byte within 64B row
    size_t off = (size_t)(r >> 7) * 65536 + (size_t)kc * 4096 + rl * 32 + (kb >> 1);
    unsigned short* dI = lab ? mA : mD;      // img -> A (pos) or D (neg)
    unsigned short* dT = lab ? mC : mB;      // txt -> C (pos) or B (neg)
    *(u16x8*)(dI + off) = oi;
    *(u16x8*)(dT + off) = ot;
    if (lab && g == 0) dA[r] = part;
}

__device__ __forceinline__ void gl16(const unsigned short* src, unsigned short* lds) {
    __builtin_amdgcn_global_load_lds((const __attribute__((address_space(1))) void*)src,
                                     (__attribute__((address_space(3))) void*)lds, 16, 0, 0);
}

#define VM4()  asm volatile("s_waitcnt vmcnt(4)" ::: "memory")
#define VM0()  asm volatile("s_waitcnt vmcnt(0)" ::: "memory")
#define BARR() asm volatile("s_barrier" ::: "memory")

// K3: 128x128x(K=512) bf16 MFMA GEMM — round-5 structure verbatim (4 waves,
// BK=32, 2-buf 32KB LDS, VM4 counted-vmcnt publish-barrier pipeline,
// 0-conflict swizzled ds_read_b128, shfl epilogue) + XCD-aware block swizzle
// (the ONE delta this round; proven FETCH-halver in rounds 6/7).
__global__ __launch_bounds__(256) void k_gemm(
        const unsigned short* __restrict__ mA, const unsigned short* __restrict__ mB,
        const unsigned short* __restrict__ mC, const unsigned short* __restrict__ mD,
        const float* __restrict__ dA, const int* __restrict__ cnts,
        float* __restrict__ rA0, float* __restrict__ rB0,
        float* __restrict__ rA1, float* __restrict__ rB1) {
    // XCD swizzle: lin -> (xcd chunk of 1024) -> per-chunk 16x16 2D tiles
    int lin = blockIdx.x + (blockIdx.y << 6) + (blockIdx.z << 12);
    int swz = ((lin & 7) << 10) + (lin >> 3);
    int z = swz >> 12;
    int s = swz & 4095;
    int cy = s >> 10;          // y-slice of 16
    int loc = s & 1023;
    int tquad = loc >> 8;      // x-quarter of 16
    int u = loc & 255;
    int nx = (tquad << 4) + (u & 15);
    int ny = (cy << 4) + (u >> 4);

    int P = cnts[0], Nn = cnts[1];
    int bm = nx * 128, bn = ny * 128;
    if (bm >= P || bn >= Nn) return;
    const unsigned short* Ap = (z ? mC : mA) + (size_t)nx * 65536;
    const unsigned short* Bp = (z ? mD : mB) + (size_t)ny * 65536;
    float* rA = z ? rA1 : rA0;
    float* rB = z ? rB1 : rB0;

    __shared__ __align__(16) unsigned short S[2][2][4096];   // [buf][A/B][128x32]

    int tid = threadIdx.x;
    int lane = tid & 63;
    int wid = tid >> 6;
    int wr = wid >> 1, wc = wid & 1;          // wave tile 64x64
    int soff = tid * 8;                        // staging ushort offset (linear)

    int kswz = ((lane >> 4) * 16) ^ ((lane & 6) << 3);
    int abyte = (wr * 64 + (lane & 15)) * 64 + kswz;   // A frag m: +m*1024
    int bbyte = (wc * 64 + (lane & 15)) * 64 + kswz;   // B frag n: +n*1024

    f32x4 acc[4][4];
#pragma unroll
    for (int m = 0; m < 4; ++m)
#pragma unroll
        for (int n = 0; n < 4; ++n) acc[m][n] = (f32x4){0.f, 0.f, 0.f, 0.f};

#define STAGE(kt, p) do { \
        gl16(Ap + (kt) * 4096 + soff,        &S[p][0][soff]); \
        gl16(Ap + (kt) * 4096 + soff + 2048, &S[p][0][soff + 2048]); \
        gl16(Bp + (kt) * 4096 + soff,        &S[p][1][soff]); \
        gl16(Bp + (kt) * 4096 + soff + 2048, &S[p][1][soff + 2048]); } while (0)

    STAGE(0, 0);
    STAGE(1, 1);
    VM4();                 // own tile-0 loads landed (tile-1's 4 still in flight)
    BARR();                // publish tile 0

#pragma unroll
    for (int kt = 0; kt < 16; ++kt) {
        const int cur = kt & 1;
        bf16x8 af[4], bfv[4];
#pragma unroll
        for (int m = 0; m < 4; ++m)
            af[m] = *(const bf16x8*)((const char*)&S[cur][0][0] + abyte + m * 1024);
#pragma unroll
        for (int n = 0; n < 4; ++n)
            bfv[n] = *(const bf16x8*)((const char*)&S[cur][1][0] + bbyte + n * 1024);
#pragma unroll
        for (int m = 0; m < 4; ++m)
#pragma unroll
            for (int n = 0; n < 4; ++n)
                acc[m][n] = __builtin_amdgcn_mfma_f32_16x16x32_bf16(af[m], bfv[n], acc[m][n], 0, 0, 0);
        if (kt < 15) {
            BARR();                            // all waves consumed S[cur]
            if (kt + 2 < 16) {
                STAGE(kt + 2, cur);            // refill cur with tile kt+2
                VM4();                         // tile kt+1 landed (own loads)
            } else {
                VM0();                         // tail
            }
            BARR();                            // publish tile kt+1
        }
    }
#undef STAGE

    // epilogue: e = exp((s - diag_row)/T); per-row sums of e and e*(s-diag_row)
    int rowbase = bm + wr * 64;
    int colb = bn + wc * 64 + (lane & 15);
    int rsub = (lane >> 4) * 4;
#pragma unroll
    for (int m = 0; m < 4; ++m) {
#pragma unroll
        for (int r = 0; r < 4; ++r) {
            int grow = rowbase + m * 16 + rsub + r;
            float dv = dA[grow];
            float pa = 0.f, pb = 0.f;
#pragma unroll
            for (int n = 0; n < 4; ++n) {
                int gcol = colb + n * 16;
                float s = acc[m][n][r];
                float df = s - dv;
                float e = (gcol < Nn) ? __expf(df * INV_TEMP) : 0.f;
                pa += e;
                pb += e * df;
            }
            pa += __shfl_xor(pa, 1); pa += __shfl_xor(pa, 2);
            pa += __shfl_xor(pa, 4); pa += __shfl_xor(pa, 8);
            pb += __shfl_xor(pb, 1); pb += __shfl_xor(pb, 2);
            pb += __shfl_xor(pb, 4); pb += __shfl_xor(pb, 8);
            if ((lane & 15) == 0 && grow < P) {
                atomicAdd(&rA[grow], pa);
                atomicAdd(&rB[grow], pb);
            }
        }
    }
}

// K4: per-positive finalize: g, s-update, per-row losses, winner atomicMax
__global__ void k_posfin(const int* __restrict__ cnts, const int* __restrict__ pos,
                         const float* __restrict__ rA0, const float* __restrict__ rB0,
                         const float* __restrict__ rA1, const float* __restrict__ rB1,
                         const int* __restrict__ image_ids, const int* __restrict__ text_ids,
                         const float* __restrict__ sIin, const float* __restrict__ sTin,
                         const int* __restrict__ epochp,
                         float* __restrict__ sIv, float* __restrict__ sTv,
                         int* __restrict__ winI, int* __restrict__ winT,
                         float* __restrict__ acc) {
    int k = blockIdx.x * 256 + threadIdx.x;
    int P = cnts[0], Nn = cnts[1];
    float invNn = 1.f / (float)Nn;
    int epoch = epochp[0];
    float lI = 0.f, lT = 0.f;
    if (k < P) {
        int i = pos[k];
        int idI = image_ids[i], idT = text_ids[i];
        float gI = rA0[k] * invNn;
        float sIvk = (epoch == 0) ? gI : 0.2f * sIin[idI] + 0.8f * gI;
        lI = (rB0[k] * invNn) / (sIvk + EPSF);
        float gT = rA1[k] * invNn;
        float sTvk = (epoch == 0) ? gT : 0.2f * sTin[idT] + 0.8f * gT;
        lT = (rB1[k] * invNn) / (sTvk + EPSF);
        sIv[k] = sIvk;
        sTv[k] = sTvk;
        atomicMax(&winI[idI], k);
        atomicMax(&winT[idT], k);
    }
    for (int off = 32; off; off >>= 1) { lI += __shfl_xor(lI, off); lT += __shfl_xor(lT, off); }
    if ((threadIdx.x & 63) == 0) {
        atomicAdd(&acc[0], lI);
        atomicAdd(&acc[1], lT);
    }
}

// K5: last-occurrence-wins scatter into output s arrays
__global__ void k_scatter(const int* __restrict__ cnts, const int* __restrict__ pos,
                          const int* __restrict__ image_ids, const int* __restrict__ text_ids,
                          const int* __restrict__ winI, const int* __restrict__ winT,
                          const float* __restrict__ sIv, const float* __restrict__ sTv,
                          float* __restrict__ out) {
    int k = blockIdx.x * 256 + threadIdx.x;
    int P = cnts[0];
    if (k < P) {
        int i = pos[k];
        int a = image_ids[i];
        if (winI[a] == k) out[1 + a] = sIv[k];
        int b = text_ids[i];
        if (winT[b] == k) out[1 + NIDS + b] = sTv[k];
    }
}

// K6: CE branch: logits, log_softmax over 5 classes, segment sums
__global__ __launch_bounds__(256) void k_ce(const float* __restrict__ imgc,
                                            const float* __restrict__ tfc,
                                            const int* __restrict__ labels,
                                            const float* __restrict__ lastl,
                                            float* __restrict__ acc) {
    __shared__ float tS[NCT * DD];
    __shared__ float sce[NCT], scn[NCT], sls[NCT];
    int tid = threadIdx.x;
    for (int j = tid; j < NCT * DD; j += 256) tS[j] = tfc[j];
    if (tid < NCT) { sce[tid] = 0.f; scn[tid] = 0.f; sls[tid] = 0.f; }
    __syncthreads();
    int lane = tid & 63;
    int wid = tid >> 6;
    for (int it = 0; it < 16; ++it) {
        int r = it * 256 + blockIdx.x * 4 + wid;
        const float4* ip = (const float4*)(imgc + (size_t)r * DD) + lane * 2;
        float4 a0 = ip[0], a1 = ip[1];
        float p[NCT];
#pragma unroll
        for (int c = 0; c < NCT; ++c) {
            const float* t = &tS[c * DD + lane * 8];
            p[c] = a0.x * t[0] + a0.y * t[1] + a0.z * t[2] + a0.w * t[3]
                 + a1.x * t[4] + a1.y * t[5] + a1.z * t[6] + a1.w * t[7];
        }
#pragma unroll
        for (int c = 0; c < NCT; ++c)
            for (int off = 32; off; off >>= 1) p[c] += __shfl_xor(p[c], off);
        if (lane == 0) {
            float l[NCT];
            float mx = -1e30f;
#pragma unroll
            for (int c = 0; c < NCT; ++c) { l[c] = p[c] * 10.0f; mx = fmaxf(mx, l[c]); }
            float ssum = 0.f;
#pragma unroll
            for (int c = 0; c < NCT; ++c) ssum += __expf(l[c] - mx);
            float lse = mx + __logf(ssum);
            int lb = labels[r];
            float ce = lse - l[lb];
            atomicAdd(&sce[lb], ce);
            atomicAdd(&scn[lb], 1.f);
            atomicAdd(&sls[lb], lastl[r]);
        }
    }
    __syncthreads();
    if (tid < NCT) {
        atomicAdd(&acc[2 + tid], sce[tid]);
        atomicAdd(&acc[7 + tid], scn[tid]);
        atomicAdd(&acc[12 + tid], sls[tid]);
    }
}

// K7: final scalar assembly: contrastive + constraint, u_new
__global__ void k_final(const int* __restrict__ cnts, const float* __restrict__ acc,
                        const float* __restrict__ u, float* __restrict__ out) {
    if (threadIdx.x == 0) {
        float P = (float)cnts[0];
        float contrast = acc[0] / P + acc[1] / P;
        float u_sum = 0.f;
        float mc[NCT], cv[NCT], u_new[NCT];
        bool pres[NCT];
#pragma unroll
        for (int c = 0; c < NCT; ++c) {
            float cn = acc[7 + c];
            pres[c] = cn > 0.f;
            float safe = fmaxf(cn, 1.f);
            mc[c] = acc[2 + c] / safe;
            float ml = acc[12 + c] / safe;
            cv[c] = mc[c] - ml;
            if (pres[c]) u_sum += u[c];
        }
        float np_ = 0.f, csum = 0.f;
#pragma unroll
        for (int c = 0; c < NCT; ++c) {
            float uu = (u_sum == 0.f) ? cv[c] : 0.2f * u[c] + 0.8f * cv[c];
            u_new[c] = pres[c] ? uu : u[c];
            if (pres[c]) {
                np_ += 1.f;
                csum += fmaxf(40.0f * u_new[c], 0.f) * mc[c] * 0.1f;
            }
            out[1 + 2 * NIDS + c] = u_new[c];
        }
        out[0] = contrast + csum / np_;
    }
}

extern "C" void kernel_launch(void* const* d_in, const int* in_sizes, int n_in,
                              void* d_out, int out_size, void* d_ws, size_t ws_size,
                              hipStream_t stream) {
    const float* img = (const float*)d_in[0];
    const float* txt = (const float*)d_in[1];
    const int* image_ids = (const int*)d_in[2];
    const int* text_ids = (const int*)d_in[3];
    const int* slabel = (const int*)d_in[4];
    const int* epoch = (const int*)d_in[5];
    const float* imgc = (const float*)d_in[6];
    const float* tfc = (const float*)d_in[7];
    const int* labels = (const int*)d_in[8];
    const float* lastl = (const float*)d_in[9];
    const float* sI = (const float*)d_in[10];
    const float* sT = (const float*)d_in[11];
    const float* u = (const float*)d_in[12];
    float* out = (float*)d_out;
    char* ws = (char*)d_ws;

    int* pos = (int*)(ws + OFF_POS);
    int* rnk = (int*)(ws + OFF_RNK);
    int* cnts = (int*)(ws + OFF_CNT);
    float* acc = (float*)(ws + OFF_ACC);
    float* dA = (float*)(ws + OFF_DA);
    float* rA0 = (float*)(ws + OFF_RA0);
    float* rB0 = (float*)(ws + OFF_RB0);
    float* rA1 = (float*)(ws + OFF_RA1);
    float* rB1 = (float*)(ws + OFF_RB1);
    float* sIv = (float*)(ws + OFF_SIV);
    float* sTv = (float*)(ws + OFF_STV);
    int* winI = (int*)(ws + OFF_WINI);
    int* winT = (int*)(ws + OFF_WINT);
    unsigned short* mA = (unsigned short*)(ws + OFF_MA);
    unsigned short* mB = (unsigned short*)(ws + OFF_MB);
    unsigned short* mC = (unsigned short*)(ws + OFF_MC);
    unsigned short* mD = (unsigned short*)(ws + OFF_MD);

    k_init<<<(NIDS + 255) / 256, 256, 0, stream>>>(sI, sT, out, winI, winT, rA0, rB0, rA1, rB1, acc);
    k_compact<<<1, 1024, 0, stream>>>(slabel, pos, rnk, cnts);
    k_gather<<<2048, 256, 0, stream>>>(img, txt, slabel, rnk, mA, mB, mC, mD, dA);
    k_gemm<<<dim3(64, 64, 2), 256, 0, stream>>>(mA, mB, mC, mD, dA, cnts, rA0, rB0, rA1, rB1);
    k_posfin<<<32, 256, 0, stream>>>(cnts, pos, rA0, rB0, rA1, rB1, image_ids, text_ids,
                                     sI, sT, epoch, sIv, sTv, winI, winT, acc);
    k_scatter<<<32, 256, 0, stream>>>(cnts, pos, image_ids, text_ids, winI, winT, sIv, sTv, out);
    k_ce<<<64, 256, 0, stream>>>(imgc, tfc, labels, lastl, acc);
    k_final<<<1, 64, 0, stream>>>(cnts, acc, u, out);
}

// Round 9
// 100.596 us; speedup vs baseline: 1.6366x; 1.6366x over previous
//
#include <hip/hip_runtime.h>

#define NBATCH 8192
#define DD 512
#define NIDS 1000000
#define BCNT 4096
#define NCT 5
#define INV_TEMP 14.285714285714286f
#define EPSF 1.1920929e-07f

typedef __attribute__((ext_vector_type(8))) short bf16x8;
typedef __attribute__((ext_vector_type(4))) float f32x4;
typedef __attribute__((ext_vector_type(8))) unsigned short u16x8;

// ---------------- workspace layout (bytes) ----------------
#define OFF_POS    ((size_t)(32*1024))
#define OFF_RNK    ((size_t)(64*1024))
#define OFF_CNT    ((size_t)(96*1024))
#define OFF_ACC    ((size_t)(97*1024))
#define OFF_DA     ((size_t)(100*1024))
#define OFF_RA0    ((size_t)(132*1024))
#define OFF_RB0    ((size_t)(164*1024))
#define OFF_RA1    ((size_t)(196*1024))
#define OFF_RB1    ((size_t)(228*1024))
#define OFF_SIV    ((size_t)(260*1024))
#define OFF_STV    ((size_t)(292*1024))
#define OFF_WINI   ((size_t)(324*1024))
#define OFF_WINT   (OFF_WINI + 4000000)
#define OFF_MA     (OFF_WINT + 4000000)
#define MATB       ((size_t)(8192*512*2))
#define OFF_MB     (OFF_MA + MATB)
#define OFF_MC     (OFF_MB + MATB)
#define OFF_MD     (OFF_MC + MATB)

// Blocked-swizzled operand layout (proven 0-conflict in rounds 4-8):
// panel = row/128 (stride 65536 ushorts), K-tile kc = k/32 (stride 4096 ushorts),
// within-tile row-major [128][32] ushorts (64B rows); byte within row:
// (granule*16) ^ ((row&6)<<3)  — applied identically by writer and reader.

__device__ __forceinline__ unsigned short f2bf(float x) {
    unsigned int u = __float_as_uint(x);
    unsigned int r = (u + 0x7fffu + ((u >> 16) & 1u)) >> 16;
    return (unsigned short)r;
}

// K0: copy s_I/s_T into output, init winner arrays and accumulators
__global__ void k_init(const float* __restrict__ sI, const float* __restrict__ sT,
                       float* __restrict__ out, int* __restrict__ winI, int* __restrict__ winT,
                       float* __restrict__ rA0, float* __restrict__ rB0,
                       float* __restrict__ rA1, float* __restrict__ rB1,
                       float* __restrict__ acc) {
    int i = blockIdx.x * blockDim.x + threadIdx.x;
    if (i < NIDS) {
        out[1 + i] = sI[i];
        out[1 + NIDS + i] = sT[i];
        winI[i] = -1;
        winT[i] = -1;
    }
    if (i < NBATCH) { rA0[i] = 0.f; rB0[i] = 0.f; rA1[i] = 0.f; rB1[i] = 0.f; }
    if (i < 32) acc[i] = 0.f;
}

// K1: single-block stable compaction: pos list, rank array, counts
__global__ void k_compact(const int* __restrict__ slabel, int* __restrict__ pos,
                          int* __restrict__ rnk, int* __restrict__ cnts) {
    __shared__ int sums[1024];
    int tid = threadIdx.x;
    int flags[8];
    int c = 0;
    int base = tid * 8;
#pragma unroll
    for (int j = 0; j < 8; ++j) { flags[j] = (slabel[base + j] == 1); c += flags[j]; }
    sums[tid] = c;
    __syncthreads();
    for (int off = 1; off < 1024; off <<= 1) {
        int add = (tid >= off) ? sums[tid - off] : 0;
        __syncthreads();
        sums[tid] += add;
        __syncthreads();
    }
    int p = sums[tid] - c;  // exclusive prefix of pos count
#pragma unroll
    for (int j = 0; j < 8; ++j) {
        int idx = base + j;
        if (flags[j]) { pos[p] = idx; rnk[idx] = p; p++; }
        else rnk[idx] = idx - p;
    }
    if (tid == 0) { cnts[0] = sums[1023]; cnts[1] = NBATCH - sums[1023]; }
}

// K2: fused gather: read img[i],txt[i] once, diag dot, bf16-convert, route to
// (mA,mC) for pos rows / (mD,mB) for neg rows in blocked-swizzled layout.
__global__ __launch_bounds__(256) void k_gather(
        const float* __restrict__ img, const float* __restrict__ txt,
        const int* __restrict__ slabel, const int* __restrict__ rnk,
        unsigned short* __restrict__ mA, unsigned short* __restrict__ mB,
        unsigned short* __restrict__ mC, unsigned short* __restrict__ mD,
        float* __restrict__ dA) {
    int tid = threadIdx.x;
    int i = blockIdx.x * 4 + (tid >> 6);     // one wave per batch row
    int g = tid & 63;                         // 16B granule
    const float4* ip = (const float4*)(img + (size_t)i * DD) + g * 2;
    const float4* tp = (const float4*)(txt + (size_t)i * DD) + g * 2;
    float4 v0 = ip[0], v1 = ip[1], t0 = tp[0], t1 = tp[1];
    float part = v0.x * t0.x + v0.y * t0.y + v0.z * t0.z + v0.w * t0.w
               + v1.x * t1.x + v1.y * t1.y + v1.z * t1.z + v1.w * t1.w;
    for (int off = 32; off; off >>= 1) part += __shfl_xor(part, off);

    int lab = (slabel[i] == 1);
    int r = rnk[i];
    u16x8 oi, ot;
    oi[0] = f2bf(v0.x); oi[1] = f2bf(v0.y); oi[2] = f2bf(v0.z); oi[3] = f2bf(v0.w);
    oi[4] = f2bf(v1.x); oi[5] = f2bf(v1.y); oi[6] = f2bf(v1.z); oi[7] = f2bf(v1.w);
    ot[0] = f2bf(t0.x); ot[1] = f2bf(t0.y); ot[2] = f2bf(t0.z); ot[3] = f2bf(t0.w);
    ot[4] = f2bf(t1.x); ot[5] = f2bf(t1.y); ot[6] = f2bf(t1.z); ot[7] = f2bf(t1.w);

    int kc = g >> 2, gg = g & 3, rl = r & 127;
    int kb = (gg * 16) ^ ((rl & 6) << 3);    // swizzled byte within 64B row
    size_t off = (size_t)(r >> 7) * 65536 + (size_t)kc * 4096 + rl * 32 + (kb >> 1);
    unsigned short* dI = lab ? mA : mD;      // img -> A (pos) or D (neg)
    unsigned short* dT = lab ? mC : mB;      // txt -> C (pos) or B (neg)
    *(u16x8*)(dI + off) = oi;
    *(u16x8*)(dT + off) = ot;
    if (lab && g == 0) dA[r] = part;
}

__device__ __forceinline__ void gl16(const unsigned short* src, unsigned short* lds) {
    __builtin_amdgcn_global_load_lds((const __attribute__((address_space(1))) void*)src,
                                     (__attribute__((address_space(3))) void*)lds, 16, 0, 0);
}

#define VM4()  asm volatile("s_waitcnt vmcnt(4)" ::: "memory")
#define VM0()  asm volatile("s_waitcnt vmcnt(0)" ::: "memory")
#define BARR() asm volatile("s_barrier" ::: "memory")

// K3: 128x128x(K=512) bf16 MFMA GEMM — round-5 main loop verbatim (4 waves,
// BK=32, 2-buf, VM4 counted-vmcnt publish-barrier pipeline, 0-conflict
// swizzled ds_read_b128, PLAIN blockIdx mapping — no XCD swizzle) + the ONE
// delta this round: LDS-staged epilogue reduction (r7-proven-exact, 36KB).
__global__ __launch_bounds__(256) void k_gemm(
        const unsigned short* __restrict__ mA, const unsigned short* __restrict__ mB,
        const unsigned short* __restrict__ mC, const unsigned short* __restrict__ mD,
        const float* __restrict__ dA, const int* __restrict__ cnts,
        float* __restrict__ rA0, float* __restrict__ rB0,
        float* __restrict__ rA1, float* __restrict__ rB1) {
    int P = cnts[0], Nn = cnts[1];
    int bm = blockIdx.x * 128, bn = blockIdx.y * 128;
    if (bm >= P || bn >= Nn) return;
    int z = blockIdx.z;
    const unsigned short* Ap = (z ? mC : mA) + (size_t)blockIdx.x * 65536;
    const unsigned short* Bp = (z ? mD : mB) + (size_t)blockIdx.y * 65536;
    float* rA = z ? rA1 : rA0;
    float* rB = z ? rB1 : rB0;

    __shared__ __align__(16) char SRAW[36864];   // 32KB staging / 36KB epilogue
    unsigned short* S0 = (unsigned short*)SRAW;  // buf p at +p*8192, B-half at +4096 (ushorts)

    int tid = threadIdx.x;
    int lane = tid & 63;
    int wid = tid >> 6;
    int wr = wid >> 1, wc = wid & 1;          // wave tile 64x64
    int soff = tid * 8;                        // staging ushort offset (linear)

    int kswz = ((lane >> 4) * 16) ^ ((lane & 6) << 3);
    int abyte = (wr * 64 + (lane & 15)) * 64 + kswz;   // A frag m: +m*1024
    int bbyte = (wc * 64 + (lane & 15)) * 64 + kswz;   // B frag n: +n*1024

    f32x4 acc[4][4];
#pragma unroll
    for (int m = 0; m < 4; ++m)
#pragma unroll
        for (int n = 0; n < 4; ++n) acc[m][n] = (f32x4){0.f, 0.f, 0.f, 0.f};

#define STAGE(kt, p) do { \
        gl16(Ap + (kt) * 4096 + soff,        S0 + (p) * 8192 + soff); \
        gl16(Ap + (kt) * 4096 + soff + 2048, S0 + (p) * 8192 + soff + 2048); \
        gl16(Bp + (kt) * 4096 + soff,        S0 + (p) * 8192 + 4096 + soff); \
        gl16(Bp + (kt) * 4096 + soff + 2048, S0 + (p) * 8192 + 4096 + soff + 2048); } while (0)

    STAGE(0, 0);
    STAGE(1, 1);
    VM4();                 // own tile-0 loads landed (tile-1's 4 still in flight)
    BARR();                // publish tile 0

#pragma unroll
    for (int kt = 0; kt < 16; ++kt) {
        const int cur = kt & 1;
        bf16x8 af[4], bfv[4];
#pragma unroll
        for (int m = 0; m < 4; ++m)
            af[m] = *(const bf16x8*)((const char*)S0 + cur * 16384 + abyte + m * 1024);
#pragma unroll
        for (int n = 0; n < 4; ++n)
            bfv[n] = *(const bf16x8*)((const char*)S0 + cur * 16384 + 8192 + bbyte + n * 1024);
#pragma unroll
        for (int m = 0; m < 4; ++m)
#pragma unroll
            for (int n = 0; n < 4; ++n)
                acc[m][n] = __builtin_amdgcn_mfma_f32_16x16x32_bf16(af[m], bfv[n], acc[m][n], 0, 0, 0);
        if (kt < 15) {
            BARR();                            // all waves consumed S[cur]
            if (kt + 2 < 16) {
                STAGE(kt + 2, cur);            // refill cur with tile kt+2
                VM4();                         // tile kt+1 landed (own loads)
            } else {
                VM0();                         // tail
            }
            BARR();                            // publish tile kt+1
        }
    }
#undef STAGE

    // ---- epilogue: e = exp((s-diag)/T); row-sums of e and e*df via LDS ----
    BARR();                                    // all waves done with staging LDS
    float* F = (float*)SRAW;                   // row R = wc*128+wr*64+wrow, stride 36, 16x(pa,pb)
    int col = lane & 15;
    int rsub = (lane >> 4) * 4;
    int rowbase = bm + wr * 64;
    int colb = bn + wc * 64 + col;
    int fb = ((wc << 7) + (wr << 6)) * 36 + col * 2;
#pragma unroll
    for (int m = 0; m < 4; ++m) {
#pragma unroll
        for (int r = 0; r < 4; ++r) {
            int wrow = m * 16 + rsub + r;
            float dv = dA[rowbase + wrow];
            float pa = 0.f, pb = 0.f;
#pragma unroll
            for (int n = 0; n < 4; ++n) {
                int gcol = colb + n * 16;
                float sv = acc[m][n][r];
                float df = sv - dv;
                float e = (gcol < Nn) ? __expf(df * INV_TEMP) : 0.f;
                pa += e;
                pb += e * df;
            }
            *(float2*)&F[fb + wrow * 36] = make_float2(pa, pb);
        }
    }
    BARR();
    // reduce: thread -> (row = tid>>1 in [0,128), half = tid&1); 8 x b128 + 1 shfl
    {
        int row = tid >> 1;
        int half = tid & 1;
        const float4* Fr = (const float4*)&F[((half << 7) + row) * 36];
        float sa = 0.f, sb = 0.f;
#pragma unroll
        for (int q = 0; q < 8; ++q) {
            float4 v = Fr[q];
            sa += v.x + v.z;
            sb += v.y + v.w;
        }
        sa += __shfl_xor(sa, 1);
        sb += __shfl_xor(sb, 1);
        int grow = bm + row;
        if (!half && grow < P) {
            atomicAdd(&rA[grow], sa);
            atomicAdd(&rB[grow], sb);
        }
    }
}

// K4: per-positive finalize: g, s-update, per-row losses, winner atomicMax
__global__ void k_posfin(const int* __restrict__ cnts, const int* __restrict__ pos,
                         const float* __restrict__ rA0, const float* __restrict__ rB0,
                         const float* __restrict__ rA1, const float* __restrict__ rB1,
                         const int* __restrict__ image_ids, const int* __restrict__ text_ids,
                         const float* __restrict__ sIin, const float* __restrict__ sTin,
                         const int* __restrict__ epochp,
                         float* __restrict__ sIv, float* __restrict__ sTv,
                         int* __restrict__ winI, int* __restrict__ winT,
                         float* __restrict__ acc) {
    int k = blockIdx.x * 256 + threadIdx.x;
    int P = cnts[0], Nn = cnts[1];
    float invNn = 1.f / (float)Nn;
    int epoch = epochp[0];
    float lI = 0.f, lT = 0.f;
    if (k < P) {
        int i = pos[k];
        int idI = image_ids[i], idT = text_ids[i];
        float gI = rA0[k] * invNn;
        float sIvk = (epoch == 0) ? gI : 0.2f * sIin[idI] + 0.8f * gI;
        lI = (rB0[k] * invNn) / (sIvk + EPSF);
        float gT = rA1[k] * invNn;
        float sTvk = (epoch == 0) ? gT : 0.2f * sTin[idT] + 0.8f * gT;
        lT = (rB1[k] * invNn) / (sTvk + EPSF);
        sIv[k] = sIvk;
        sTv[k] = sTvk;
        atomicMax(&winI[idI], k);
        atomicMax(&winT[idT], k);
    }
    for (int off = 32; off; off >>= 1) { lI += __shfl_xor(lI, off); lT += __shfl_xor(lT, off); }
    if ((threadIdx.x & 63) == 0) {
        atomicAdd(&acc[0], lI);
        atomicAdd(&acc[1], lT);
    }
}

// K5: last-occurrence-wins scatter into output s arrays
__global__ void k_scatter(const int* __restrict__ cnts, const int* __restrict__ pos,
                          const int* __restrict__ image_ids, const int* __restrict__ text_ids,
                          const int* __restrict__ winI, const int* __restrict__ winT,
                          const float* __restrict__ sIv, const float* __restrict__ sTv,
                          float* __restrict__ out) {
    int k = blockIdx.x * 256 + threadIdx.x;
    int P = cnts[0];
    if (k < P) {
        int i = pos[k];
        int a = image_ids[i];
        if (winI[a] == k) out[1 + a] = sIv[k];
        int b = text_ids[i];
        if (winT[b] == k) out[1 + NIDS + b] = sTv[k];
    }
}

// K6: CE branch: logits, log_softmax over 5 classes, segment sums
__global__ __launch_bounds__(256) void k_ce(const float* __restrict__ imgc,
                                            const float* __restrict__ tfc,
                                            const int* __restrict__ labels,
                                            const float* __restrict__ lastl,
                                            float* __restrict__ acc) {
    __shared__ float tS[NCT * DD];
    __shared__ float sce[NCT], scn[NCT], sls[NCT];
    int tid = threadIdx.x;
    for (int j = tid; j < NCT * DD; j += 256) tS[j] = tfc[j];
    if (tid < NCT) { sce[tid] = 0.f; scn[tid] = 0.f; sls[tid] = 0.f; }
    __syncthreads();
    int lane = tid & 63;
    int wid = tid >> 6;
    for (int it = 0; it < 16; ++it) {
        int r = it * 256 + blockIdx.x * 4 + wid;
        const float4* ip = (const float4*)(imgc + (size_t)r * DD) + lane * 2;
        float4 a0 = ip[0], a1 = ip[1];
        float p[NCT];
#pragma unroll
        for (int c = 0; c < NCT; ++c) {
            const float* t = &tS[c * DD + lane * 8];
            p[c] = a0.x * t[0] + a0.y * t[1] + a0.z * t[2] + a0.w * t[3]
                 + a1.x * t[4] + a1.y * t[5] + a1.z * t[6] + a1.w * t[7];
        }
#pragma unroll
        for (int c = 0; c < NCT; ++c)
            for (int off = 32; off; off >>= 1) p[c] += __shfl_xor(p[c], off);
        if (lane == 0) {
            float l[NCT];
            float mx = -1e30f;
#pragma unroll
            for (int c = 0; c < NCT; ++c) { l[c] = p[c] * 10.0f; mx = fmaxf(mx, l[c]); }
            float ssum = 0.f;
#pragma unroll
            for (int c = 0; c < NCT; ++c) ssum += __expf(l[c] - mx);
            float lse = mx + __logf(ssum);
            int lb = labels[r];
            float ce = lse - l[lb];
            atomicAdd(&sce[lb], ce);
            atomicAdd(&scn[lb], 1.f);
            atomicAdd(&sls[lb], lastl[r]);
        }
    }
    __syncthreads();
    if (tid < NCT) {
        atomicAdd(&acc[2 + tid], sce[tid]);
        atomicAdd(&acc[7 + tid], scn[tid]);
        atomicAdd(&acc[12 + tid], sls[tid]);
    }
}

// K7: final scalar assembly: contrastive + constraint, u_new
__global__ void k_final(const int* __restrict__ cnts, const float* __restrict__ acc,
                        const float* __restrict__ u, float* __restrict__ out) {
    if (threadIdx.x == 0) {
        float P = (float)cnts[0];
        float contrast = acc[0] / P + acc[1] / P;
        float u_sum = 0.f;
        float mc[NCT], cv[NCT], u_new[NCT];
        bool pres[NCT];
#pragma unroll
        for (int c = 0; c < NCT; ++c) {
            float cn = acc[7 + c];
            pres[c] = cn > 0.f;
            float safe = fmaxf(cn, 1.f);
            mc[c] = acc[2 + c] / safe;
            float ml = acc[12 + c] / safe;
            cv[c] = mc[c] - ml;
            if (pres[c]) u_sum += u[c];
        }
        float np_ = 0.f, csum = 0.f;
#pragma unroll
        for (int c = 0; c < NCT; ++c) {
            float uu = (u_sum == 0.f) ? cv[c] : 0.2f * u[c] + 0.8f * cv[c];
            u_new[c] = pres[c] ? uu : u[c];
            if (pres[c]) {
                np_ += 1.f;
                csum += fmaxf(40.0f * u_new[c], 0.f) * mc[c] * 0.1f;
            }
            out[1 + 2 * NIDS + c] = u_new[c];
        }
        out[0] = contrast + csum / np_;
    }
}

extern "C" void kernel_launch(void* const* d_in, const int* in_sizes, int n_in,
                              void* d_out, int out_size, void* d_ws, size_t ws_size,
                              hipStream_t stream) {
    const float* img = (const float*)d_in[0];
    const float* txt = (const float*)d_in[1];
    const int* image_ids = (const int*)d_in[2];
    const int* text_ids = (const int*)d_in[3];
    const int* slabel = (const int*)d_in[4];
    const int* epoch = (const int*)d_in[5];
    const float* imgc = (const float*)d_in[6];
    const float* tfc = (const float*)d_in[7];
    const int* labels = (const int*)d_in[8];
    const float* lastl = (const float*)d_in[9];
    const float* sI = (const float*)d_in[10];
    const float* sT = (const float*)d_in[11];
    const float* u = (const float*)d_in[12];
    float* out = (float*)d_out;
    char* ws = (char*)d_ws;

    int* pos = (int*)(ws + OFF_POS);
    int* rnk = (int*)(ws + OFF_RNK);
    int* cnts = (int*)(ws + OFF_CNT);
    float* acc = (float*)(ws + OFF_ACC);
    float* dA = (float*)(ws + OFF_DA);
    float* rA0 = (float*)(ws + OFF_RA0);
    float* rB0 = (float*)(ws + OFF_RB0);
    float* rA1 = (float*)(ws + OFF_RA1);
    float* rB1 = (float*)(ws + OFF_RB1);
    float* sIv = (float*)(ws + OFF_SIV);
    float* sTv = (float*)(ws + OFF_STV);
    int* winI = (int*)(ws + OFF_WINI);
    int* winT = (int*)(ws + OFF_WINT);
    unsigned short* mA = (unsigned short*)(ws + OFF_MA);
    unsigned short* mB = (unsigned short*)(ws + OFF_MB);
    unsigned short* mC = (unsigned short*)(ws + OFF_MC);
    unsigned short* mD = (unsigned short*)(ws + OFF_MD);

    k_init<<<(NIDS + 255) / 256, 256, 0, stream>>>(sI, sT, out, winI, winT, rA0, rB0, rA1, rB1, acc);
    k_compact<<<1, 1024, 0, stream>>>(slabel, pos, rnk, cnts);
    k_gather<<<2048, 256, 0, stream>>>(img, txt, slabel, rnk, mA, mB, mC, mD, dA);
    k_gemm<<<dim3(64, 64, 2), 256, 0, stream>>>(mA, mB, mC, mD, dA, cnts, rA0, rB0, rA1, rB1);
    k_posfin<<<32, 256, 0, stream>>>(cnts, pos, rA0, rB0, rA1, rB1, image_ids, text_ids,
                                     sI, sT, epoch, sIv, sTv, winI, winT, acc);
    k_scatter<<<32, 256, 0, stream>>>(cnts, pos, image_ids, text_ids, winI, winT, sIv, sTv, out);
    k_ce<<<64, 256, 0, stream>>>(imgc, tfc, labels, lastl, acc);
    k_final<<<1, 64, 0, stream>>>(cnts, acc, u, out);
}

// Round 10
// 87.978 us; speedup vs baseline: 1.8714x; 1.1434x over previous
//
#include <hip/hip_runtime.h>

#define NBATCH 8192
#define DD 512
#define NIDS 1000000
#define BCNT 4096
#define NCT 5
#define INV_TEMP 14.285714285714286f
#define EPSF 1.1920929e-07f

typedef __attribute__((ext_vector_type(8))) short bf16x8;
typedef __attribute__((ext_vector_type(4))) float f32x4;
typedef __attribute__((ext_vector_type(8))) unsigned short u16x8;

// ---------------- workspace layout (bytes) ----------------
#define OFF_LP     ((size_t)0)            // 256 floats: 32 blk x 4 wave x (lI,lT)
#define OFF_CE1    ((size_t)1024)         // 320 floats: CE sum partials
#define OFF_CE2    ((size_t)2304)         // 320 floats: count partials
#define OFF_CE3    ((size_t)3584)         // 320 floats: last-loss partials
#define OFF_POS    ((size_t)(32*1024))
#define OFF_RNK    ((size_t)(64*1024))
#define OFF_CNT    ((size_t)(96*1024))
#define OFF_DA     ((size_t)(100*1024))
#define OFF_RA0    ((size_t)(132*1024))
#define OFF_RB0    ((size_t)(164*1024))
#define OFF_RA1    ((size_t)(196*1024))
#define OFF_RB1    ((size_t)(228*1024))
#define OFF_SIV    ((size_t)(260*1024))
#define OFF_STV    ((size_t)(292*1024))
#define OFF_WINI   ((size_t)(324*1024))
#define OFF_WINT   (OFF_WINI + 4000000)
#define OFF_MA     (OFF_WINT + 4000000)
#define MATB       ((size_t)(8192*512*2))
#define OFF_MB     (OFF_MA + MATB)
#define OFF_MC     (OFF_MB + MATB)
#define OFF_MD     (OFF_MC + MATB)

// Blocked-swizzled operand layout (proven 0-conflict in rounds 4-9):
// panel = row/128 (stride 65536 ushorts), K-tile kc = k/32 (stride 4096 ushorts),
// within-tile row-major [128][32] ushorts (64B rows); byte within row:
// (granule*16) ^ ((row&6)<<3)  — applied identically by writer and reader.

__device__ __forceinline__ unsigned short f2bf(float x) {
    unsigned int u = __float_as_uint(x);
    unsigned int r = (u + 0x7fffu + ((u >> 16) & 1u)) >> 16;
    return (unsigned short)r;
}

// K1 (fused front-end): blocks 0..3906 init-only; blocks 3907..3970 CE with
// per-block partial outputs; block 3971 does the pos/neg compaction.
__global__ __launch_bounds__(256) void k_pre(
        const float* __restrict__ sI, const float* __restrict__ sT,
        float* __restrict__ out, int* __restrict__ winI, int* __restrict__ winT,
        float* __restrict__ rA0, float* __restrict__ rB0,
        float* __restrict__ rA1, float* __restrict__ rB1,
        const int* __restrict__ slabel, int* __restrict__ pos,
        int* __restrict__ rnk, int* __restrict__ cnts,
        const float* __restrict__ imgc, const float* __restrict__ tfc,
        const int* __restrict__ labels, const float* __restrict__ lastl,
        float* __restrict__ ce1, float* __restrict__ ce2, float* __restrict__ ce3) {
    int bid = blockIdx.x;
    int tid = threadIdx.x;
    // ---- init slice (s copy, winners, row-accumulator zero) ----
    int iv = bid * 256 + tid;
    if (iv < NIDS) {
        out[1 + iv] = sI[iv];
        out[1 + NIDS + iv] = sT[iv];
        winI[iv] = -1;
        winT[iv] = -1;
    }
    if (iv < NBATCH) { rA0[iv] = 0.f; rB0[iv] = 0.f; rA1[iv] = 0.f; rB1[iv] = 0.f; }
    if (bid < 3907) return;

    if (bid == 3971) {
        // ---- compaction: 256 threads x 32 items, stable scan ----
        __shared__ int sums[256];
        int base = tid * 32;
        int c = 0;
        for (int j = 0; j < 32; ++j) c += (slabel[base + j] == 1);
        sums[tid] = c;
        __syncthreads();
        for (int off = 1; off < 256; off <<= 1) {
            int add = (tid >= off) ? sums[tid - off] : 0;
            __syncthreads();
            sums[tid] += add;
            __syncthreads();
        }
        int p = sums[tid] - c;   // exclusive prefix of pos count
        for (int j = 0; j < 32; ++j) {
            int idx = base + j;
            if (slabel[idx] == 1) { pos[p] = idx; rnk[idx] = p; p++; }
            else rnk[idx] = idx - p;
        }
        if (tid == 255) { cnts[0] = sums[255]; cnts[1] = NBATCH - sums[255]; }
    } else {
        // ---- CE block cb in [0,64): 4 rows/iter x 16 iters; partial outputs ----
        int cb = bid - 3907;
        __shared__ float tS[NCT * DD];
        __shared__ float sce[NCT], scn[NCT], sls[NCT];
        for (int j = tid; j < NCT * DD; j += 256) tS[j] = tfc[j];
        if (tid < NCT) { sce[tid] = 0.f; scn[tid] = 0.f; sls[tid] = 0.f; }
        __syncthreads();
        int lane = tid & 63;
        int wid = tid >> 6;
        for (int it = 0; it < 16; ++it) {
            int r = it * 256 + cb * 4 + wid;
            const float4* ip = (const float4*)(imgc + (size_t)r * DD) + lane * 2;
            float4 a0 = ip[0], a1 = ip[1];
            float p[NCT];
#pragma unroll
            for (int c = 0; c < NCT; ++c) {
                const float* t = &tS[c * DD + lane * 8];
                p[c] = a0.x * t[0] + a0.y * t[1] + a0.z * t[2] + a0.w * t[3]
                     + a1.x * t[4] + a1.y * t[5] + a1.z * t[6] + a1.w * t[7];
            }
#pragma unroll
            for (int c = 0; c < NCT; ++c)
                for (int off = 32; off; off >>= 1) p[c] += __shfl_xor(p[c], off);
            if (lane == 0) {
                float l[NCT];
                float mx = -1e30f;
#pragma unroll
                for (int c = 0; c < NCT; ++c) { l[c] = p[c] * 10.0f; mx = fmaxf(mx, l[c]); }
                float ssum = 0.f;
#pragma unroll
                for (int c = 0; c < NCT; ++c) ssum += __expf(l[c] - mx);
                float lse = mx + __logf(ssum);
                int lb = labels[r];
                float ce = lse - l[lb];
                atomicAdd(&sce[lb], ce);
                atomicAdd(&scn[lb], 1.f);
                atomicAdd(&sls[lb], lastl[r]);
            }
        }
        __syncthreads();
        if (tid < NCT) {
            ce1[cb * 5 + tid] = sce[tid];
            ce2[cb * 5 + tid] = scn[tid];
            ce3[cb * 5 + tid] = sls[tid];
        }
    }
}

// K2: fused gather: read img[i],txt[i] once, diag dot, bf16-convert, route to
// (mA,mC) for pos rows / (mD,mB) for neg rows in blocked-swizzled layout.
__global__ __launch_bounds__(256) void k_gather(
        const float* __restrict__ img, const float* __restrict__ txt,
        const int* __restrict__ slabel, const int* __restrict__ rnk,
        unsigned short* __restrict__ mA, unsigned short* __restrict__ mB,
        unsigned short* __restrict__ mC, unsigned short* __restrict__ mD,
        float* __restrict__ dA) {
    int tid = threadIdx.x;
    int i = blockIdx.x * 4 + (tid >> 6);     // one wave per batch row
    int g = tid & 63;                         // 16B granule
    const float4* ip = (const float4*)(img + (size_t)i * DD) + g * 2;
    const float4* tp = (const float4*)(txt + (size_t)i * DD) + g * 2;
    float4 v0 = ip[0], v1 = ip[1], t0 = tp[0], t1 = tp[1];
    float part = v0.x * t0.x + v0.y * t0.y + v0.z * t0.z + v0.w * t0.w
               + v1.x * t1.x + v1.y * t1.y + v1.z * t1.z + v1.w * t1.w;
    for (int off = 32; off; off >>= 1) part += __shfl_xor(part, off);

    int lab = (slabel[i] == 1);
    int r = rnk[i];
    u16x8 oi, ot;
    oi[0] = f2bf(v0.x); oi[1] = f2bf(v0.y); oi[2] = f2bf(v0.z); oi[3] = f2bf(v0.w);
    oi[4] = f2bf(v1.x); oi[5] = f2bf(v1.y); oi[6] = f2bf(v1.z); oi[7] = f2bf(v1.w);
    ot[0] = f2bf(t0.x); ot[1] = f2bf(t0.y); ot[2] = f2bf(t0.z); ot[3] = f2bf(t0.w);
    ot[4] = f2bf(t1.x); ot[5] = f2bf(t1.y); ot[6] = f2bf(t1.z); ot[7] = f2bf(t1.w);

    int kc = g >> 2, gg = g & 3, rl = r & 127;
    int kb = (gg * 16) ^ ((rl & 6) << 3);    // swizzled byte within 64B row
    size_t off = (size_t)(r >> 7) * 65536 + (size_t)kc * 4096 + rl * 32 + (kb >> 1);
    unsigned short* dI = lab ? mA : mD;      // img -> A (pos) or D (neg)
    unsigned short* dT = lab ? mC : mB;      // txt -> C (pos) or B (neg)
    *(u16x8*)(dI + off) = oi;
    *(u16x8*)(dT + off) = ot;
    if (lab && g == 0) dA[r] = part;
}

__device__ __forceinline__ void gl16(const unsigned short* src, unsigned short* lds) {
    __builtin_amdgcn_global_load_lds((const __attribute__((address_space(1))) void*)src,
                                     (__attribute__((address_space(3))) void*)lds, 16, 0, 0);
}

#define VM4()  asm volatile("s_waitcnt vmcnt(4)" ::: "memory")
#define VM0()  asm volatile("s_waitcnt vmcnt(0)" ::: "memory")
#define BARR() asm volatile("s_barrier" ::: "memory")

// K3: 128x128x(K=512) bf16 MFMA GEMM — BYTE-IDENTICAL to round 9 (the control):
// 4 waves, BK=32, 2-buf, VM4 counted-vmcnt publish-barrier pipeline, 0-conflict
// swizzled ds_read_b128, plain blockIdx mapping, LDS-staged epilogue (36KB).
__global__ __launch_bounds__(256) void k_gemm(
        const unsigned short* __restrict__ mA, const unsigned short* __restrict__ mB,
        const unsigned short* __restrict__ mC, const unsigned short* __restrict__ mD,
        const float* __restrict__ dA, const int* __restrict__ cnts,
        float* __restrict__ rA0, float* __restrict__ rB0,
        float* __restrict__ rA1, float* __restrict__ rB1) {
    int P = cnts[0], Nn = cnts[1];
    int bm = blockIdx.x * 128, bn = blockIdx.y * 128;
    if (bm >= P || bn >= Nn) return;
    int z = blockIdx.z;
    const unsigned short* Ap = (z ? mC : mA) + (size_t)blockIdx.x * 65536;
    const unsigned short* Bp = (z ? mD : mB) + (size_t)blockIdx.y * 65536;
    float* rA = z ? rA1 : rA0;
    float* rB = z ? rB1 : rB0;

    __shared__ __align__(16) char SRAW[36864];   // 32KB staging / 36KB epilogue
    unsigned short* S0 = (unsigned short*)SRAW;  // buf p at +p*8192, B-half at +4096 (ushorts)

    int tid = threadIdx.x;
    int lane = tid & 63;
    int wid = tid >> 6;
    int wr = wid >> 1, wc = wid & 1;          // wave tile 64x64
    int soff = tid * 8;                        // staging ushort offset (linear)

    int kswz = ((lane >> 4) * 16) ^ ((lane & 6) << 3);
    int abyte = (wr * 64 + (lane & 15)) * 64 + kswz;   // A frag m: +m*1024
    int bbyte = (wc * 64 + (lane & 15)) * 64 + kswz;   // B frag n: +n*1024

    f32x4 acc[4][4];
#pragma unroll
    for (int m = 0; m < 4; ++m)
#pragma unroll
        for (int n = 0; n < 4; ++n) acc[m][n] = (f32x4){0.f, 0.f, 0.f, 0.f};

#define STAGE(kt, p) do { \
        gl16(Ap + (kt) * 4096 + soff,        S0 + (p) * 8192 + soff); \
        gl16(Ap + (kt) * 4096 + soff + 2048, S0 + (p) * 8192 + soff + 2048); \
        gl16(Bp + (kt) * 4096 + soff,        S0 + (p) * 8192 + 4096 + soff); \
        gl16(Bp + (kt) * 4096 + soff + 2048, S0 + (p) * 8192 + 4096 + soff + 2048); } while (0)

    STAGE(0, 0);
    STAGE(1, 1);
    VM4();                 // own tile-0 loads landed (tile-1's 4 still in flight)
    BARR();                // publish tile 0

#pragma unroll
    for (int kt = 0; kt < 16; ++kt) {
        const int cur = kt & 1;
        bf16x8 af[4], bfv[4];
#pragma unroll
        for (int m = 0; m < 4; ++m)
            af[m] = *(const bf16x8*)((const char*)S0 + cur * 16384 + abyte + m * 1024);
#pragma unroll
        for (int n = 0; n < 4; ++n)
            bfv[n] = *(const bf16x8*)((const char*)S0 + cur * 16384 + 8192 + bbyte + n * 1024);
#pragma unroll
        for (int m = 0; m < 4; ++m)
#pragma unroll
            for (int n = 0; n < 4; ++n)
                acc[m][n] = __builtin_amdgcn_mfma_f32_16x16x32_bf16(af[m], bfv[n], acc[m][n], 0, 0, 0);
        if (kt < 15) {
            BARR();                            // all waves consumed S[cur]
            if (kt + 2 < 16) {
                STAGE(kt + 2, cur);            // refill cur with tile kt+2
                VM4();                         // tile kt+1 landed (own loads)
            } else {
                VM0();                         // tail
            }
            BARR();                            // publish tile kt+1
        }
    }
#undef STAGE

    // ---- epilogue: e = exp((s-diag)/T); row-sums of e and e*df via LDS ----
    BARR();                                    // all waves done with staging LDS
    float* F = (float*)SRAW;                   // row R = wc*128+wr*64+wrow, stride 36, 16x(pa,pb)
    int col = lane & 15;
    int rsub = (lane >> 4) * 4;
    int rowbase = bm + wr * 64;
    int colb = bn + wc * 64 + col;
    int fb = ((wc << 7) + (wr << 6)) * 36 + col * 2;
#pragma unroll
    for (int m = 0; m < 4; ++m) {
#pragma unroll
        for (int r = 0; r < 4; ++r) {
            int wrow = m * 16 + rsub + r;
            float dv = dA[rowbase + wrow];
            float pa = 0.f, pb = 0.f;
#pragma unroll
            for (int n = 0; n < 4; ++n) {
                int gcol = colb + n * 16;
                float sv = acc[m][n][r];
                float df = sv - dv;
                float e = (gcol < Nn) ? __expf(df * INV_TEMP) : 0.f;
                pa += e;
                pb += e * df;
            }
            *(float2*)&F[fb + wrow * 36] = make_float2(pa, pb);
        }
    }
    BARR();
    // reduce: thread -> (row = tid>>1 in [0,128), half = tid&1); 8 x b128 + 1 shfl
    {
        int row = tid >> 1;
        int half = tid & 1;
        const float4* Fr = (const float4*)&F[((half << 7) + row) * 36];
        float sa = 0.f, sb = 0.f;
#pragma unroll
        for (int q = 0; q < 8; ++q) {
            float4 v = Fr[q];
            sa += v.x + v.z;
            sb += v.y + v.w;
        }
        sa += __shfl_xor(sa, 1);
        sb += __shfl_xor(sb, 1);
        int grow = bm + row;
        if (!half && grow < P) {
            atomicAdd(&rA[grow], sa);
            atomicAdd(&rB[grow], sb);
        }
    }
}

// K4: per-positive finalize: g, s-update, per-row losses (per-wave partial
// stores — no global accumulator zeroing needed), winner atomicMax
__global__ void k_posfin(const int* __restrict__ cnts, const int* __restrict__ pos,
                         const float* __restrict__ rA0, const float* __restrict__ rB0,
                         const float* __restrict__ rA1, const float* __restrict__ rB1,
                         const int* __restrict__ image_ids, const int* __restrict__ text_ids,
                         const float* __restrict__ sIin, const float* __restrict__ sTin,
                         const int* __restrict__ epochp,
                         float* __restrict__ sIv, float* __restrict__ sTv,
                         int* __restrict__ winI, int* __restrict__ winT,
                         float* __restrict__ lp) {
    int k = blockIdx.x * 256 + threadIdx.x;
    int P = cnts[0], Nn = cnts[1];
    float invNn = 1.f / (float)Nn;
    int epoch = epochp[0];
    float lI = 0.f, lT = 0.f;
    if (k < P) {
        int i = pos[k];
        int idI = image_ids[i], idT = text_ids[i];
        float gI = rA0[k] * invNn;
        float sIvk = (epoch == 0) ? gI : 0.2f * sIin[idI] + 0.8f * gI;
        lI = (rB0[k] * invNn) / (sIvk + EPSF);
        float gT = rA1[k] * invNn;
        float sTvk = (epoch == 0) ? gT : 0.2f * sTin[idT] + 0.8f * gT;
        lT = (rB1[k] * invNn) / (sTvk + EPSF);
        sIv[k] = sIvk;
        sTv[k] = sTvk;
        atomicMax(&winI[idI], k);
        atomicMax(&winT[idT], k);
    }
    for (int off = 32; off; off >>= 1) { lI += __shfl_xor(lI, off); lT += __shfl_xor(lT, off); }
    if ((threadIdx.x & 63) == 0) {
        int slot = blockIdx.x * 4 + (threadIdx.x >> 6);
        lp[slot * 2] = lI;
        lp[slot * 2 + 1] = lT;
    }
}

// K5: scatter (last-occurrence-wins) + partial reductions + final scalars
__global__ void k_fin(const int* __restrict__ cnts, const int* __restrict__ pos,
                      const int* __restrict__ image_ids, const int* __restrict__ text_ids,
                      const int* __restrict__ winI, const int* __restrict__ winT,
                      const float* __restrict__ sIv, const float* __restrict__ sTv,
                      const float* __restrict__ lp, const float* __restrict__ ce1,
                      const float* __restrict__ ce2, const float* __restrict__ ce3,
                      const float* __restrict__ u, float* __restrict__ out) {
    int P = cnts[0];
    int k = blockIdx.x * 256 + threadIdx.x;
    if (k < P) {
        int i = pos[k];
        int a = image_ids[i];
        if (winI[a] == k) out[1 + a] = sIv[k];
        int b = text_ids[i];
        if (winT[b] == k) out[1 + NIDS + b] = sTv[k];
    }
    if (blockIdx.x == 0 && threadIdx.x < 64) {
        int lane = threadIdx.x;
        float lI = lp[2 * lane] + lp[2 * (lane + 64)];
        float lT = lp[2 * lane + 1] + lp[2 * (lane + 64) + 1];
        for (int off = 32; off; off >>= 1) { lI += __shfl_xor(lI, off); lT += __shfl_xor(lT, off); }
        float ce[NCT], cn[NCT], ls[NCT];
#pragma unroll
        for (int c = 0; c < NCT; ++c) {
            float a1 = ce1[lane * 5 + c], a2 = ce2[lane * 5 + c], a3 = ce3[lane * 5 + c];
            for (int off = 32; off; off >>= 1) {
                a1 += __shfl_xor(a1, off);
                a2 += __shfl_xor(a2, off);
                a3 += __shfl_xor(a3, off);
            }
            ce[c] = a1; cn[c] = a2; ls[c] = a3;
        }
        if (lane == 0) {
            float Pf = (float)P;
            float contrast = lI / Pf + lT / Pf;
            float u_sum = 0.f;
            float mc[NCT], cv[NCT], u_new[NCT];
            bool pres[NCT];
#pragma unroll
            for (int c = 0; c < NCT; ++c) {
                pres[c] = cn[c] > 0.f;
                float safe = fmaxf(cn[c], 1.f);
                mc[c] = ce[c] / safe;
                float ml = ls[c] / safe;
                cv[c] = mc[c] - ml;
                if (pres[c]) u_sum += u[c];
            }
            float np_ = 0.f, csum = 0.f;
#pragma unroll
            for (int c = 0; c < NCT; ++c) {
                float uu = (u_sum == 0.f) ? cv[c] : 0.2f * u[c] + 0.8f * cv[c];
                u_new[c] = pres[c] ? uu : u[c];
                if (pres[c]) {
                    np_ += 1.f;
                    csum += fmaxf(40.0f * u_new[c], 0.f) * mc[c] * 0.1f;
                }
                out[1 + 2 * NIDS + c] = u_new[c];
            }
            out[0] = contrast + csum / np_;
        }
    }
}

extern "C" void kernel_launch(void* const* d_in, const int* in_sizes, int n_in,
                              void* d_out, int out_size, void* d_ws, size_t ws_size,
                              hipStream_t stream) {
    const float* img = (const float*)d_in[0];
    const float* txt = (const float*)d_in[1];
    const int* image_ids = (const int*)d_in[2];
    const int* text_ids = (const int*)d_in[3];
    const int* slabel = (const int*)d_in[4];
    const int* epoch = (const int*)d_in[5];
    const float* imgc = (const float*)d_in[6];
    const float* tfc = (const float*)d_in[7];
    const int* labels = (const int*)d_in[8];
    const float* lastl = (const float*)d_in[9];
    const float* sI = (const float*)d_in[10];
    const float* sT = (const float*)d_in[11];
    const float* u = (const float*)d_in[12];
    float* out = (float*)d_out;
    char* ws = (char*)d_ws;

    float* lp = (float*)(ws + OFF_LP);
    float* ce1 = (float*)(ws + OFF_CE1);
    float* ce2 = (float*)(ws + OFF_CE2);
    float* ce3 = (float*)(ws + OFF_CE3);
    int* pos = (int*)(ws + OFF_POS);
    int* rnk = (int*)(ws + OFF_RNK);
    int* cnts = (int*)(ws + OFF_CNT);
    float* dA = (float*)(ws + OFF_DA);
    float* rA0 = (float*)(ws + OFF_RA0);
    float* rB0 = (float*)(ws + OFF_RB0);
    float* rA1 = (float*)(ws + OFF_RA1);
    float* rB1 = (float*)(ws + OFF_RB1);
    float* sIv = (float*)(ws + OFF_SIV);
    float* sTv = (float*)(ws + OFF_STV);
    int* winI = (int*)(ws + OFF_WINI);
    int* winT = (int*)(ws + OFF_WINT);
    unsigned short* mA = (unsigned short*)(ws + OFF_MA);
    unsigned short* mB = (unsigned short*)(ws + OFF_MB);
    unsigned short* mC = (unsigned short*)(ws + OFF_MC);
    unsigned short* mD = (unsigned short*)(ws + OFF_MD);

    k_pre<<<3972, 256, 0, stream>>>(sI, sT, out, winI, winT, rA0, rB0, rA1, rB1,
                                    slabel, pos, rnk, cnts,
                                    imgc, tfc, labels, lastl, ce1, ce2, ce3);
    k_gather<<<2048, 256, 0, stream>>>(img, txt, slabel, rnk, mA, mB, mC, mD, dA);
    k_gemm<<<dim3(64, 64, 2), 256, 0, stream>>>(mA, mB, mC, mD, dA, cnts, rA0, rB0, rA1, rB1);
    k_posfin<<<32, 256, 0, stream>>>(cnts, pos, rA0, rB0, rA1, rB1, image_ids, text_ids,
                                     sI, sT, epoch, sIv, sTv, winI, winT, lp);
    k_fin<<<32, 256, 0, stream>>>(cnts, pos, image_ids, text_ids, winI, winT,
                                  sIv, sTv, lp, ce1, ce2, ce3, u, out);
}